// Round 11
// baseline (6880.299 us; speedup 1.0000x reference)
//
#include <hip/hip_runtime.h>
#include <hip/hip_bf16.h>
#include <stdint.h>

#define T_STEPS 512
#define NBATCH 64
#define HID 1024
#define NGATE 4096
#define NLAYERS 2
#define BH (NBATCH * HID)            // 65536
#define TBH (T_STEPS * NBATCH * HID) // 33554432
#define WEL ((size_t)NLAYERS * NGATE * HID)
#define NBLK 256

typedef __attribute__((ext_vector_type(8))) short short8;
typedef __attribute__((ext_vector_type(4))) float f32x4;

__device__ __forceinline__ ushort f2bf(float f) {
  union { float f; uint32_t i; } u; u.f = f;
  return (ushort)((u.i + 0x7fffu + ((u.i >> 16) & 1u)) >> 16);  // RNE
}

// ---- A-load pipe: 16 rotating slots, counted vmcnt, 32 loads per wave-step.
// ISSC = cached load (x, h0 ring: addresses never rewritten within dispatch).
// ISSU = sc0 sc1 cross-XCD-coherent (h1 double buffer, addresses reused).
// VMW ties the slot reg through the wait ("+v") -> MFMA data-depends on the WAIT.
// CORRECTNESS PRECONDITION (round-10 lesson): the steady loop must contain NO
// other VMEM (spill/remat) -- guaranteed by the 1-block/CU occupancy forcing
// (LDS > 80 KB) + launch_bounds(512,2) giving a 256-VGPR budget > ~176 demand.
#define ISSC(S, M, OFF) \
  asm volatile("global_load_dwordx4 %0, %1, off offset:" #OFF \
               : "=v"(fr[S]) : "v"(aP[M]));
#define ISSU(S, M, OFF) \
  asm volatile("global_load_dwordx4 %0, %1, off offset:" #OFF " sc0 sc1" \
               : "=v"(fr[S]) : "v"(aP[M]));
#define VMW(N, SLOT) \
  asm volatile("s_waitcnt vmcnt(" #N ")" : "+v"(fr[SLOT]));
#define CON(S, M, KC) { \
    accA[M] = __builtin_amdgcn_mfma_f32_16x16x32_bf16(fr[S], breg[0][KC], accA[M], 0, 0, 0); \
    accB[M] = __builtin_amdgcn_mfma_f32_16x16x32_bf16(fr[S], breg[1][KC], accB[M], 0, 0, 0); }

// issue order = consume order: slot = kc*4+m (m fastest). B-frags are registers.
#define PIPE(I) \
  I(0,0,0)    I(1,1,0)    I(2,2,0)    I(3,3,0)   \
  I(4,0,64)   I(5,1,64)   I(6,2,64)   I(7,3,64)  \
  I(8,0,128)  I(9,1,128)  I(10,2,128) I(11,3,128)\
  I(12,0,192) I(13,1,192) I(14,2,192) I(15,3,192)\
  VMW(15,0)  CON(0,0,0)  I(0,0,256)  \
  VMW(15,1)  CON(1,1,0)  I(1,1,256)  \
  VMW(15,2)  CON(2,2,0)  I(2,2,256)  \
  VMW(15,3)  CON(3,3,0)  I(3,3,256)  \
  VMW(15,4)  CON(4,0,1)  I(4,0,320)  \
  VMW(15,5)  CON(5,1,1)  I(5,1,320)  \
  VMW(15,6)  CON(6,2,1)  I(6,2,320)  \
  VMW(15,7)  CON(7,3,1)  I(7,3,320)  \
  VMW(15,8)  CON(8,0,2)  I(8,0,384)  \
  VMW(15,9)  CON(9,1,2)  I(9,1,384)  \
  VMW(15,10) CON(10,2,2) I(10,2,384) \
  VMW(15,11) CON(11,3,2) I(11,3,384) \
  VMW(15,12) CON(12,0,3) I(12,0,448) \
  VMW(15,13) CON(13,1,3) I(13,1,448) \
  VMW(15,14) CON(14,2,3) I(14,2,448) \
  VMW(15,15) CON(15,3,3) I(15,3,448) \
  VMW(15,0)  CON(0,0,4)  \
  VMW(14,1)  CON(1,1,4)  \
  VMW(13,2)  CON(2,2,4)  \
  VMW(12,3)  CON(3,3,4)  \
  VMW(11,4)  CON(4,0,5)  \
  VMW(10,5)  CON(5,1,5)  \
  VMW(9,6)   CON(6,2,5)  \
  VMW(8,7)   CON(7,3,5)  \
  VMW(7,8)   CON(8,0,6)  \
  VMW(6,9)   CON(9,1,6)  \
  VMW(5,10)  CON(10,2,6) \
  VMW(4,11)  CON(11,3,6) \
  VMW(3,12)  CON(12,0,7) \
  VMW(2,13)  CON(13,1,7) \
  VMW(1,14)  CON(14,2,7) \
  VMW(0,15)  CON(15,3,7)

// ---------------- elementwise helpers ----------------
__global__ void k_f32_to_bf16(const float* __restrict__ in, ushort* __restrict__ out, int n) {
  int i = (blockIdx.x * blockDim.x + threadIdx.x) * 4;
  if (i >= n) return;
  const float4 v = *reinterpret_cast<const float4*>(in + i);
  ushort4 o; o.x = f2bf(v.x); o.y = f2bf(v.y); o.z = f2bf(v.z); o.w = f2bf(v.w);
  *reinterpret_cast<ushort4*>(out + i) = o;
}
__global__ void k_zero(int* p, int n) {
  int i = blockIdx.x * blockDim.x + threadIdx.x;
  if (i < n) p[i] = 0;
}

// ---------------- persistent fused scan ----------------
struct ScanP {
  const ushort* wih; const ushort* whh;
  const ushort* xb;  const ushort* hinit;
  ushort* h0r;                            // layer-0 h ring (T_STEPS slots)
  ushort* h1d;                            // layer-1 h double buffer
  const float* c0; const float* bi; const float* bh;
  float* out; int* bar;
};

// Root+release barrier (monotonic, relaxed-only, no resets). Proven r8/r9.
__device__ __forceinline__ void gbar(int* bar, int phase, int stripe, bool isRoot) {
  __syncthreads();
  if (threadIdx.x == 0) {
    __hip_atomic_fetch_add(bar + stripe * 16, 1, __ATOMIC_RELAXED, __HIP_MEMORY_SCOPE_AGENT);
    if (isRoot) {
      const int target = (phase + 1) * NBLK;
      for (;;) {
        int sum = 0;
#pragma unroll
        for (int i = 0; i < 16; ++i)
          sum += __hip_atomic_load(bar + i * 16, __ATOMIC_RELAXED, __HIP_MEMORY_SCOPE_AGENT);
        if (sum >= target) break;
        __builtin_amdgcn_s_sleep(1);
      }
      __hip_atomic_store(bar + 256, phase + 1, __ATOMIC_RELAXED, __HIP_MEMORY_SCOPE_AGENT);
    } else {
      while (__hip_atomic_load(bar + 256, __ATOMIC_RELAXED, __HIP_MEMORY_SCOPE_AGENT) < phase + 1)
        __builtin_amdgcn_s_sleep(2);
    }
  }
  __syncthreads();
  __builtin_amdgcn_sched_barrier(0);
}

// 256 blocks x 512 threads (8 waves). Blocks 0..127 = layer0 step s; 128..255 =
// layer1 step s-1. Wave w: K-slice (w&3)*256 of source (w<4 ? lowK : highK).
// B fragments (W slice) live in REGISTERS (64 VGPR/lane); LDS carries only the
// per-wave partial C tiles. LDS is deliberately padded past 80 KB so the
// compiler's occupancy model matches reality (1 block/CU) and grants the
// 256-VGPR budget -- at 69 KB it targeted 2 blocks/CU, capped us at ~128 regs,
// and spilled breg into the steady loop, poisoning the counted-vmcnt pipe (r10).
__global__ __launch_bounds__(512, 2) void k_scan(ScanP p) {
  __shared__ float glds[8][32][100];  // 102,400 B: row stride 100 (==4 mod 32 banks)
  const int tid = threadIdx.x, wave = tid >> 6, lane = tid & 63;
  const bool isL1 = blockIdx.x >= 128;
  const int cb = isL1 ? (int)blockIdx.x - 128 : (int)blockIdx.x;
  const int j0 = cb * 8;
  const int stripe = blockIdx.x & 15;
  const bool isRoot = (blockIdx.x == 0);
  const bool hiSrc = wave >= 4;
  const int koff = (wave & 3) * 256;

  // ---- B preload into registers (W static across all steps) ----
  const ushort* wihL = p.wih + (isL1 ? (size_t)NGATE * HID : 0);
  const ushort* whhL = p.whh + (isL1 ? (size_t)NGATE * HID : 0);
  const ushort* bsrc = hiSrc ? whhL : wihL;
  short8 breg[2][8];
#pragma unroll
  for (int t = 0; t < 2; ++t) {
    const int i = t * 16 + (lane & 15);
    const int g = (i >> 3) * 1024 + j0 + (i & 7);
    const ushort* bp = bsrc + (size_t)g * 1024 + koff + (lane >> 4) * 8;
#pragma unroll
    for (int kc = 0; kc < 8; ++kc) breg[t][kc] = *(const short8*)(bp + kc * 32);
  }

  // ---- epilogue geometry: thread -> (b = tid>>3, jl = tid&7) ----
  const int eb = tid >> 3, jl = tid & 7, jj = j0 + jl;
  const int lofs = isL1 ? NGATE : 0;
  float creg = p.c0[(isL1 ? BH : 0) + eb * 1024 + jj];
  float bias[4];
#pragma unroll
  for (int g = 0; g < 4; ++g)
    bias[g] = p.bi[lofs + g * 1024 + jj] + p.bh[lofs + g * 1024 + jj];

  const size_t arow = (size_t)(lane & 15) * 1024 + koff + (lane >> 4) * 8;

  for (int s = 0; s < T_STEPS + 1; ++s) {
    const bool act = isL1 ? (s >= 1) : (s < T_STEPS);
    if (act) {
      const ushort* src;
      if (!isL1) src = hiSrc ? ((s == 0) ? p.hinit : p.h0r + (size_t)(s - 1) * BH)
                             : (p.xb + (size_t)s * BH);
      else       src = hiSrc ? ((s == 1) ? p.hinit + BH : p.h1d + (size_t)(s & 1) * BH)
                             : (p.h0r + (size_t)(s - 1) * BH);
      const ushort* base = src + arow;
      const ushort* aP[4] = { base, base + 16 * 1024, base + 32 * 1024, base + 48 * 1024 };
      f32x4 accA[4], accB[4];
#pragma unroll
      for (int m = 0; m < 4; ++m) {
        accA[m] = (f32x4){0.f, 0.f, 0.f, 0.f};
        accB[m] = (f32x4){0.f, 0.f, 0.f, 0.f};
      }
      short8 fr[16];
      if (isL1 && hiSrc) { PIPE(ISSU) } else { PIPE(ISSC) }

      // partial C tiles -> LDS (full overwrite; col = lane&15 (+16), rows 4-contig)
      {
        const int r0 = lane & 15, q4 = (lane >> 4) * 4;
#pragma unroll
        for (int m = 0; m < 4; ++m) {
          *(f32x4*)&glds[wave][r0][m * 16 + q4]      = accA[m];
          *(f32x4*)&glds[wave][16 + r0][m * 16 + q4] = accB[m];
        }
      }
      __syncthreads();

      // epilogue: sum 8 partials (fixed order, deterministic) + bias
      float v[4];
#pragma unroll
      for (int g = 0; g < 4; ++g) {
        float t = bias[g];
#pragma unroll
        for (int w = 0; w < 8; ++w) t += glds[w][g * 8 + jl][eb];
        v[g] = t;
      }
      float c = creg;
      const float si = 1.f / (1.f + __expf(-v[0]));
      const float sf = 1.f / (1.f + __expf(-v[1]));
      const float tg = tanhf(v[2]);
      const float so = 1.f / (1.f + __expf(-v[3]));
      c = sf * c + si * tg;
      const float h = so * tanhf(c);
      creg = c;

      // h store: pack 2 bf16 per dword across thread pairs (proven r5 path)
      const uint32_t hu = (uint32_t)f2bf(h);
      const uint32_t other = __shfl_xor(hu, 1);
      ushort* hdst = (!isL1) ? (p.h0r + (size_t)s * BH)
                             : (p.h1d + (size_t)((s - 1) & 1) * BH);
      if (!(tid & 1)) {
        uint32_t* hw = (uint32_t*)(hdst + eb * 1024 + jj);
        const uint32_t packed = hu | (other << 16);
        __hip_atomic_store(hw, packed, __ATOMIC_RELAXED, __HIP_MEMORY_SCOPE_AGENT);
        uint32_t chk = __hip_atomic_load(hw, __ATOMIC_RELAXED, __HIP_MEMORY_SCOPE_AGENT);
        asm volatile("" :: "v"(chk));
      }

      if (isL1) {
        p.out[(size_t)(s - 1) * BH + eb * 1024 + jj] = h;
        if (s - 1 == T_STEPS - 1) {
          p.out[(size_t)TBH + BH + eb * 1024 + jj] = h;
          p.out[(size_t)TBH + 3 * BH + eb * 1024 + jj] = c;
        }
      } else if (s == T_STEPS - 1) {
        p.out[(size_t)TBH + eb * 1024 + jj] = h;
        p.out[(size_t)TBH + 2 * BH + eb * 1024 + jj] = c;
      }
    }
    gbar(p.bar, s, stripe, isRoot);
  }
}

// ---------------- host ----------------
extern "C" void kernel_launch(void* const* d_in, const int* in_sizes, int n_in,
                              void* d_out, int out_size, void* d_ws, size_t ws_size,
                              hipStream_t stream) {
  const float* x    = (const float*)d_in[0];
  const float* h0   = (const float*)d_in[1];
  const float* c0   = (const float*)d_in[2];
  const float* w_ih = (const float*)d_in[3];
  const float* w_hh = (const float*)d_in[4];
  const float* b_ih = (const float*)d_in[5];
  const float* b_hh = (const float*)d_in[6];
  float* out = (float*)d_out;

  ushort* xb    = (ushort*)d_ws;
  ushort* wihb  = xb + (size_t)TBH;
  ushort* whhb  = wihb + WEL;
  ushort* hinit = whhb + WEL;
  ushort* h0r   = hinit + 2 * (size_t)BH;            // ring: T_STEPS slots
  ushort* h1d   = h0r + (size_t)TBH;
  int*    bar   = (int*)(h1d + 2 * (size_t)BH);

  const size_t need = ((size_t)2 * TBH + 2 * WEL + 4 * (size_t)BH) * 2 + 4096;
  if (ws_size < need) return;  // loud failure: d_out stays poisoned

  { int n = TBH;        k_f32_to_bf16<<<(n / 4 + 255) / 256, 256, 0, stream>>>(x, xb, n); }
  { int n = (int)WEL;   k_f32_to_bf16<<<(n / 4 + 255) / 256, 256, 0, stream>>>(w_ih, wihb, n); }
  { int n = (int)WEL;   k_f32_to_bf16<<<(n / 4 + 255) / 256, 256, 0, stream>>>(w_hh, whhb, n); }
  { int n = 2 * BH;     k_f32_to_bf16<<<(n / 4 + 255) / 256, 256, 0, stream>>>(h0, hinit, n); }
  k_zero<<<2, 256, 0, stream>>>(bar, 512);

  ScanP sp;
  sp.wih = wihb; sp.whh = whhb;
  sp.xb = xb; sp.hinit = hinit;
  sp.h0r = h0r; sp.h1d = h1d;
  sp.c0 = c0; sp.bi = b_ih; sp.bh = b_hh;
  sp.out = out; sp.bar = bar;

  void* kp[1] = {&sp};
  hipLaunchCooperativeKernel(reinterpret_cast<void*>(&k_scan),
                             dim3(NBLK), dim3(512), kp, 0, stream);
}

// Round 12
// 6000.538 us; speedup vs baseline: 1.1466x; 1.1466x over previous
//
#include <hip/hip_runtime.h>
#include <hip/hip_bf16.h>
#include <stdint.h>

#define T_STEPS 512
#define NBATCH 64
#define HID 1024
#define NGATE 4096
#define NLAYERS 2
#define BH (NBATCH * HID)            // 65536
#define TBH (T_STEPS * NBATCH * HID) // 33554432
#define WEL ((size_t)NLAYERS * NGATE * HID)
#define GBLK 128                     // blocks per barrier group

typedef __attribute__((ext_vector_type(8))) short short8;
typedef __attribute__((ext_vector_type(4))) float f32x4;

__device__ __forceinline__ ushort f2bf(float f) {
  union { float f; uint32_t i; } u; u.f = f;
  return (ushort)((u.i + 0x7fffu + ((u.i >> 16) & 1u)) >> 16);  // RNE
}
__device__ __forceinline__ void gll16(const void* g, void* l) {
  __builtin_amdgcn_global_load_lds(
      (const __attribute__((address_space(1))) unsigned int*)g,
      (__attribute__((address_space(3))) unsigned int*)l, 16, 0, 0);
}

// ---- A-load pipe: 16 rotating slots, counted vmcnt (r7-proven). ALL loads are
// now normal cached loads: every steady-state source (x, h0 ring, h1 ring) is a
// never-rewritten-within-dispatch address, so per-XCD L2 dedups the broadcast.
// (r9-r11 used sc0sc1 for h1 double-buffer: 16 MB/step of L3-direct traffic on
// the critical chain -- the ring removes the address reuse that required it.)
#define ISSC(S, P, OFF) \
  asm volatile("global_load_dwordx4 %0, %1, off offset:" #OFF \
               : "=v"(fr[S]) : "v"(P));
#define VMW(N, SLOT) \
  asm volatile("s_waitcnt vmcnt(" #N ")" : "+v"(fr[SLOT]));
#define CON(SLOT, KC) { \
    const short8 b0v = *(const short8*)(bb0 + ((((KC) * 64) + kb) ^ bsw)); \
    const short8 b1v = *(const short8*)(bb1 + ((((KC) * 64) + kb) ^ bsw)); \
    accA = __builtin_amdgcn_mfma_f32_16x16x32_bf16(fr[SLOT], b0v, accA, 0, 0, 0); \
    accB = __builtin_amdgcn_mfma_f32_16x16x32_bf16(fr[SLOT], b1v, accB, 0, 0, 0); }

#define PIPE64() \
  ISSC(0,A0p,0)    ISSC(1,A0p,64)   ISSC(2,A0p,128)  ISSC(3,A0p,192)  \
  ISSC(4,A0p,256)  ISSC(5,A0p,320)  ISSC(6,A0p,384)  ISSC(7,A0p,448)  \
  ISSC(8,A0p,512)  ISSC(9,A0p,576)  ISSC(10,A0p,640) ISSC(11,A0p,704) \
  ISSC(12,A0p,768) ISSC(13,A0p,832) ISSC(14,A0p,896) ISSC(15,A0p,960) \
  VMW(15,0)  CON(0,0)   ISSC(0,A0p,1024)  \
  VMW(15,1)  CON(1,1)   ISSC(1,A0p,1088)  \
  VMW(15,2)  CON(2,2)   ISSC(2,A0p,1152)  \
  VMW(15,3)  CON(3,3)   ISSC(3,A0p,1216)  \
  VMW(15,4)  CON(4,4)   ISSC(4,A0p,1280)  \
  VMW(15,5)  CON(5,5)   ISSC(5,A0p,1344)  \
  VMW(15,6)  CON(6,6)   ISSC(6,A0p,1408)  \
  VMW(15,7)  CON(7,7)   ISSC(7,A0p,1472)  \
  VMW(15,8)  CON(8,8)   ISSC(8,A0p,1536)  \
  VMW(15,9)  CON(9,9)   ISSC(9,A0p,1600)  \
  VMW(15,10) CON(10,10) ISSC(10,A0p,1664) \
  VMW(15,11) CON(11,11) ISSC(11,A0p,1728) \
  VMW(15,12) CON(12,12) ISSC(12,A0p,1792) \
  VMW(15,13) CON(13,13) ISSC(13,A0p,1856) \
  VMW(15,14) CON(14,14) ISSC(14,A0p,1920) \
  VMW(15,15) CON(15,15) ISSC(15,A0p,1984) \
  VMW(15,0)  CON(0,16)  ISSC(0,A1p,0)     \
  VMW(15,1)  CON(1,17)  ISSC(1,A1p,64)    \
  VMW(15,2)  CON(2,18)  ISSC(2,A1p,128)   \
  VMW(15,3)  CON(3,19)  ISSC(3,A1p,192)   \
  VMW(15,4)  CON(4,20)  ISSC(4,A1p,256)   \
  VMW(15,5)  CON(5,21)  ISSC(5,A1p,320)   \
  VMW(15,6)  CON(6,22)  ISSC(6,A1p,384)   \
  VMW(15,7)  CON(7,23)  ISSC(7,A1p,448)   \
  VMW(15,8)  CON(8,24)  ISSC(8,A1p,512)   \
  VMW(15,9)  CON(9,25)  ISSC(9,A1p,576)   \
  VMW(15,10) CON(10,26) ISSC(10,A1p,640)  \
  VMW(15,11) CON(11,27) ISSC(11,A1p,704)  \
  VMW(15,12) CON(12,28) ISSC(12,A1p,768)  \
  VMW(15,13) CON(13,29) ISSC(13,A1p,832)  \
  VMW(15,14) CON(14,30) ISSC(14,A1p,896)  \
  VMW(15,15) CON(15,31) ISSC(15,A1p,960)  \
  VMW(15,0)  CON(0,32)  ISSC(0,A1p,1024)  \
  VMW(15,1)  CON(1,33)  ISSC(1,A1p,1088)  \
  VMW(15,2)  CON(2,34)  ISSC(2,A1p,1152)  \
  VMW(15,3)  CON(3,35)  ISSC(3,A1p,1216)  \
  VMW(15,4)  CON(4,36)  ISSC(4,A1p,1280)  \
  VMW(15,5)  CON(5,37)  ISSC(5,A1p,1344)  \
  VMW(15,6)  CON(6,38)  ISSC(6,A1p,1408)  \
  VMW(15,7)  CON(7,39)  ISSC(7,A1p,1472)  \
  VMW(15,8)  CON(8,40)  ISSC(8,A1p,1536)  \
  VMW(15,9)  CON(9,41)  ISSC(9,A1p,1600)  \
  VMW(15,10) CON(10,42) ISSC(10,A1p,1664) \
  VMW(15,11) CON(11,43) ISSC(11,A1p,1728) \
  VMW(15,12) CON(12,44) ISSC(12,A1p,1792) \
  VMW(15,13) CON(13,45) ISSC(13,A1p,1856) \
  VMW(15,14) CON(14,46) ISSC(14,A1p,1920) \
  VMW(15,15) CON(15,47) ISSC(15,A1p,1984) \
  VMW(15,0)  CON(0,48)  \
  VMW(14,1)  CON(1,49)  \
  VMW(13,2)  CON(2,50)  \
  VMW(12,3)  CON(3,51)  \
  VMW(11,4)  CON(4,52)  \
  VMW(10,5)  CON(5,53)  \
  VMW(9,6)   CON(6,54)  \
  VMW(8,7)   CON(7,55)  \
  VMW(7,8)   CON(8,56)  \
  VMW(6,9)   CON(9,57)  \
  VMW(5,10)  CON(10,58) \
  VMW(4,11)  CON(11,59) \
  VMW(3,12)  CON(12,60) \
  VMW(2,13)  CON(13,61) \
  VMW(1,14)  CON(14,62) \
  VMW(0,15)  CON(15,63)

// ---------------- elementwise helpers ----------------
__global__ void k_f32_to_bf16(const float* __restrict__ in, ushort* __restrict__ out, int n) {
  int i = (blockIdx.x * blockDim.x + threadIdx.x) * 4;
  if (i >= n) return;
  const float4 v = *reinterpret_cast<const float4*>(in + i);
  ushort4 o; o.x = f2bf(v.x); o.y = f2bf(v.y); o.z = f2bf(v.z); o.w = f2bf(v.w);
  *reinterpret_cast<ushort4*>(out + i) = o;
}
__global__ void k_zero(int* p, int n) {
  int i = blockIdx.x * blockDim.x + threadIdx.x;
  if (i < n) p[i] = 0;
}

// ---------------- persistent fused scan, decoupled layer chains ----------------
struct ScanP {
  const ushort* wih; const ushort* whh;
  const ushort* xb;  const ushort* hinit;
  ushort* h0r;                            // layer-0 h ring (T_STEPS slots)
  ushort* h1r;                            // layer-1 h ring (T_STEPS slots)
  const float* c0; const float* bi; const float* bh;
  float* out; int* bar;
};

// Per-group barrier (128 blocks): monotonic striped arrivals (16 lines x 8),
// root polls + publishes release word gb[256]. Relaxed-only, no resets (r8).
__device__ __forceinline__ void gbar(int* gb, int phase, int stripe, bool isRoot) {
  __syncthreads();
  if (threadIdx.x == 0) {
    __hip_atomic_fetch_add(gb + stripe * 16, 1, __ATOMIC_RELAXED, __HIP_MEMORY_SCOPE_AGENT);
    if (isRoot) {
      const int target = (phase + 1) * GBLK;
      for (;;) {
        int sum = 0;
#pragma unroll
        for (int i = 0; i < 16; ++i)
          sum += __hip_atomic_load(gb + i * 16, __ATOMIC_RELAXED, __HIP_MEMORY_SCOPE_AGENT);
        if (sum >= target) break;
        __builtin_amdgcn_s_sleep(1);
      }
      __hip_atomic_store(gb + 256, phase + 1, __ATOMIC_RELAXED, __HIP_MEMORY_SCOPE_AGENT);
    } else {
      while (__hip_atomic_load(gb + 256, __ATOMIC_RELAXED, __HIP_MEMORY_SCOPE_AGENT) < phase + 1)
        __builtin_amdgcn_s_sleep(2);
    }
  }
  __syncthreads();
  __builtin_amdgcn_sched_barrier(0);
}

// 256 blocks x 256 threads. Blocks 0..127 (group 0) run layer 0, steps 0..511,
// barrier-synced ONLY among themselves -- they sprint ahead of layer 1 (ring
// capacity = full sequence, no WAR hazard). Blocks 128..255 (group 1) run
// layer 1, gated one-way on group 0's release word (h0[t] published).
__global__ __launch_bounds__(256, 1) void k_scan(ScanP p) {
  __shared__ __align__(16) ushort Wl[32 * 2048];  // 128 KB
  __shared__ float glds[64 * 33];
  const int tid = threadIdx.x, wave = tid >> 6, lane = tid & 63;
  const bool isL1 = blockIdx.x >= 128;
  const int cb = isL1 ? (int)blockIdx.x - 128 : (int)blockIdx.x;
  const int j0 = cb * 8;
  const int stripe = cb & 15;
  const bool isRoot = (cb == 0);
  int* gb = p.bar + (isL1 ? 512 : 0);
  int* rel0 = p.bar + 256;

  const ushort* wihL = p.wih + (isL1 ? (size_t)NGATE * HID : 0);
  const ushort* whhL = p.whh + (isL1 ? (size_t)NGATE * HID : 0);
  for (int q = wave; q < 128; q += 4) {
    const int i = q >> 2, ch = q & 3;
    const ushort* base = (ch < 2) ? wihL : whhL;
    const int g = (i >> 3) * 1024 + j0 + (i & 7);
    gll16(base + (size_t)g * 1024 + (ch & 1) * 512 + (((lane * 16) ^ ((i & 7) << 4)) >> 1),
          (char*)Wl + i * 4096 + ch * 1024);
  }

  // epilogue geometry: thread owns (b = tid>>2, j = j0 + (tid&3)*2 + {0,1})
  const int eb  = tid >> 2;
  const int jl0 = (tid & 3) * 2;
  const int jj  = j0 + jl0;
  const int lofs = isL1 ? NGATE : 0;
  float creg[2], bias[4][2];
#pragma unroll
  for (int i = 0; i < 2; ++i) creg[i] = p.c0[(isL1 ? BH : 0) + eb * 1024 + jj + i];
#pragma unroll
  for (int g = 0; g < 4; ++g)
#pragma unroll
    for (int i = 0; i < 2; ++i)
      bias[g][i] = p.bi[lofs + g * 1024 + jj + i] + p.bh[lofs + g * 1024 + jj + i];

  const size_t aoff = (size_t)(wave * 16 + (lane & 15)) * 1024 + (size_t)((lane >> 4) * 8);
  const int r0 = lane & 15;
  const char* bb0 = (const char*)Wl + r0 * 4096;
  const char* bb1 = (const char*)Wl + (r0 + 16) * 4096;
  const int bsw = (r0 & 7) << 4;
  const int kb = (lane >> 4) * 16;

  __syncthreads();  // W staged

  for (int t = 0; t < T_STEPS; ++t) {
    if (isL1) {  // one-way gate: need h0[t] (rel0 >= t+1). L0 never waits on L1.
      if (threadIdx.x == 0) {
        while (__hip_atomic_load(rel0, __ATOMIC_RELAXED, __HIP_MEMORY_SCOPE_AGENT) < t + 1)
          __builtin_amdgcn_s_sleep(2);
      }
      __syncthreads();
      __builtin_amdgcn_sched_barrier(0);
    }

    f32x4 accA = {0.f, 0.f, 0.f, 0.f}, accB = {0.f, 0.f, 0.f, 0.f};
    short8 fr[16];
    {
      const ushort* A0p;
      const ushort* A1p;
      if (!isL1) {
        A0p = p.xb + (size_t)t * BH + aoff;
        A1p = ((t == 0) ? p.hinit : p.h0r + (size_t)(t - 1) * BH) + aoff;
      } else {
        A0p = p.h0r + (size_t)t * BH + aoff;
        A1p = ((t == 0) ? p.hinit + BH : p.h1r + (size_t)(t - 1) * BH) + aoff;
      }
      PIPE64()
    }
#pragma unroll
    for (int r = 0; r < 4; ++r) {
      const int row = wave * 16 + (lane >> 4) * 4 + r;
      glds[row * 33 + r0]      = accA[r];
      glds[row * 33 + 16 + r0] = accB[r];
    }
    __syncthreads();

    float hres[2];
#pragma unroll
    for (int i = 0; i < 2; ++i) {
      const int jl = jl0 + i;
      const float gi = glds[eb * 33 + jl]      + bias[0][i];
      const float gf = glds[eb * 33 + 8 + jl]  + bias[1][i];
      const float gg = glds[eb * 33 + 16 + jl] + bias[2][i];
      const float go = glds[eb * 33 + 24 + jl] + bias[3][i];
      float c = creg[i];
      const float si = 1.f / (1.f + __expf(-gi));
      const float sf = 1.f / (1.f + __expf(-gf));
      const float so = 1.f / (1.f + __expf(-go));
      const float tg = tanhf(gg);
      c = sf * c + si * tg;
      hres[i] = so * tanhf(c);
      creg[i] = c;
    }

    const uint32_t packed = (uint32_t)f2bf(hres[0]) | ((uint32_t)f2bf(hres[1]) << 16);
    ushort* hdst = (!isL1) ? (p.h0r + (size_t)t * BH) : (p.h1r + (size_t)t * BH);
    uint32_t* hw = (uint32_t*)(hdst + eb * 1024 + jj);
    __hip_atomic_store(hw, packed, __ATOMIC_RELAXED, __HIP_MEMORY_SCOPE_AGENT);
    // same-address load-back: store committed at coherence point before arrive
    uint32_t chk = __hip_atomic_load(hw, __ATOMIC_RELAXED, __HIP_MEMORY_SCOPE_AGENT);
    asm volatile("" :: "v"(chk));

    if (isL1) {
#pragma unroll
      for (int i = 0; i < 2; ++i)
        p.out[(size_t)t * BH + eb * 1024 + jj + i] = hres[i];
      if (t == T_STEPS - 1) {
#pragma unroll
        for (int i = 0; i < 2; ++i) {
          p.out[(size_t)TBH + BH + eb * 1024 + jj + i] = hres[i];
          p.out[(size_t)TBH + 3 * BH + eb * 1024 + jj + i] = creg[i];
        }
      }
    } else if (t == T_STEPS - 1) {
#pragma unroll
      for (int i = 0; i < 2; ++i) {
        p.out[(size_t)TBH + eb * 1024 + jj + i] = hres[i];
        p.out[(size_t)TBH + 2 * BH + eb * 1024 + jj + i] = creg[i];
      }
    }

    gbar(gb, t, stripe, isRoot);
  }
}

// ---------------- host ----------------
extern "C" void kernel_launch(void* const* d_in, const int* in_sizes, int n_in,
                              void* d_out, int out_size, void* d_ws, size_t ws_size,
                              hipStream_t stream) {
  const float* x    = (const float*)d_in[0];
  const float* h0   = (const float*)d_in[1];
  const float* c0   = (const float*)d_in[2];
  const float* w_ih = (const float*)d_in[3];
  const float* w_hh = (const float*)d_in[4];
  const float* b_ih = (const float*)d_in[5];
  const float* b_hh = (const float*)d_in[6];
  float* out = (float*)d_out;

  ushort* xb    = (ushort*)d_ws;
  ushort* wihb  = xb + (size_t)TBH;
  ushort* whhb  = wihb + WEL;
  ushort* hinit = whhb + WEL;
  ushort* h0r   = hinit + 2 * (size_t)BH;            // ring: T_STEPS slots
  ushort* h1r   = h0r + (size_t)TBH;                 // ring: T_STEPS slots
  int*    bar   = (int*)(h1r + (size_t)TBH);

  const size_t need = ((size_t)3 * TBH + 2 * WEL + 2 * (size_t)BH) * 2 + 4096;
  if (ws_size < need) return;  // loud failure: d_out stays poisoned

  { int n = TBH;        k_f32_to_bf16<<<(n / 4 + 255) / 256, 256, 0, stream>>>(x, xb, n); }
  { int n = (int)WEL;   k_f32_to_bf16<<<(n / 4 + 255) / 256, 256, 0, stream>>>(w_ih, wihb, n); }
  { int n = (int)WEL;   k_f32_to_bf16<<<(n / 4 + 255) / 256, 256, 0, stream>>>(w_hh, whhb, n); }
  { int n = 2 * BH;     k_f32_to_bf16<<<(n / 4 + 255) / 256, 256, 0, stream>>>(h0, hinit, n); }
  k_zero<<<4, 256, 0, stream>>>(bar, 1024);

  ScanP sp;
  sp.wih = wihb; sp.whh = whhb;
  sp.xb = xb; sp.hinit = hinit;
  sp.h0r = h0r; sp.h1r = h1r;
  sp.c0 = c0; sp.bi = b_ih; sp.bh = b_hh;
  sp.out = out; sp.bar = bar;

  void* kp[1] = {&sp};
  hipLaunchCooperativeKernel(reinterpret_cast<void*>(&k_scan),
                             dim3(256), dim3(256), kp, 0, stream);
}

// Round 13
// 5552.088 us; speedup vs baseline: 1.2392x; 1.0808x over previous
//
#include <hip/hip_runtime.h>
#include <hip/hip_bf16.h>
#include <stdint.h>

#define T_STEPS 512
#define NBATCH 64
#define HID 1024
#define NGATE 4096
#define NLAYERS 2
#define BH (NBATCH * HID)            // 65536
#define TBH (T_STEPS * NBATCH * HID) // 33554432
#define WEL ((size_t)NLAYERS * NGATE * HID)
#define GBLK 128                     // blocks per barrier group

typedef __attribute__((ext_vector_type(8))) short short8;
typedef __attribute__((ext_vector_type(4))) float f32x4;

__device__ __forceinline__ ushort f2bf(float f) {
  union { float f; uint32_t i; } u; u.f = f;
  return (ushort)((u.i + 0x7fffu + ((u.i >> 16) & 1u)) >> 16);  // RNE
}
__device__ __forceinline__ void gll16(const void* g, void* l) {
  __builtin_amdgcn_global_load_lds(
      (const __attribute__((address_space(1))) unsigned int*)g,
      (__attribute__((address_space(3))) unsigned int*)l, 16, 0, 0);
}

// ---- A-load pipe: 16 rotating slots, counted vmcnt (r7-proven), all cached
// loads (every source -- x, h0 ring, h1 ring -- is never rewritten in-dispatch).
#define ISSC(S, P, OFF) \
  asm volatile("global_load_dwordx4 %0, %1, off offset:" #OFF \
               : "=v"(fr[S]) : "v"(P));
#define VMW(N, SLOT) \
  asm volatile("s_waitcnt vmcnt(" #N ")" : "+v"(fr[SLOT]));
#define CON(SLOT, KC) { \
    const short8 b0v = *(const short8*)(bb0 + ((((KC) * 64) + kb) ^ bsw)); \
    const short8 b1v = *(const short8*)(bb1 + ((((KC) * 64) + kb) ^ bsw)); \
    accA = __builtin_amdgcn_mfma_f32_16x16x32_bf16(fr[SLOT], b0v, accA, 0, 0, 0); \
    accB = __builtin_amdgcn_mfma_f32_16x16x32_bf16(fr[SLOT], b1v, accB, 0, 0, 0); }

// One K=1024 half: 32 loads/lane, fully drained at the end (vmcnt->0), so a
// scalar gate poll can sit between halves without perturbing counted waits.
#define PIPE32(Pp, KB) \
  ISSC(0,Pp,0)    ISSC(1,Pp,64)   ISSC(2,Pp,128)  ISSC(3,Pp,192)  \
  ISSC(4,Pp,256)  ISSC(5,Pp,320)  ISSC(6,Pp,384)  ISSC(7,Pp,448)  \
  ISSC(8,Pp,512)  ISSC(9,Pp,576)  ISSC(10,Pp,640) ISSC(11,Pp,704) \
  ISSC(12,Pp,768) ISSC(13,Pp,832) ISSC(14,Pp,896) ISSC(15,Pp,960) \
  VMW(15,0)  CON(0,(KB)+0)   ISSC(0,Pp,1024)  \
  VMW(15,1)  CON(1,(KB)+1)   ISSC(1,Pp,1088)  \
  VMW(15,2)  CON(2,(KB)+2)   ISSC(2,Pp,1152)  \
  VMW(15,3)  CON(3,(KB)+3)   ISSC(3,Pp,1216)  \
  VMW(15,4)  CON(4,(KB)+4)   ISSC(4,Pp,1280)  \
  VMW(15,5)  CON(5,(KB)+5)   ISSC(5,Pp,1344)  \
  VMW(15,6)  CON(6,(KB)+6)   ISSC(6,Pp,1408)  \
  VMW(15,7)  CON(7,(KB)+7)   ISSC(7,Pp,1472)  \
  VMW(15,8)  CON(8,(KB)+8)   ISSC(8,Pp,1536)  \
  VMW(15,9)  CON(9,(KB)+9)   ISSC(9,Pp,1600)  \
  VMW(15,10) CON(10,(KB)+10) ISSC(10,Pp,1664) \
  VMW(15,11) CON(11,(KB)+11) ISSC(11,Pp,1728) \
  VMW(15,12) CON(12,(KB)+12) ISSC(12,Pp,1792) \
  VMW(15,13) CON(13,(KB)+13) ISSC(13,Pp,1856) \
  VMW(15,14) CON(14,(KB)+14) ISSC(14,Pp,1920) \
  VMW(15,15) CON(15,(KB)+15) ISSC(15,Pp,1984) \
  VMW(15,0)  CON(0,(KB)+16)  \
  VMW(14,1)  CON(1,(KB)+17)  \
  VMW(13,2)  CON(2,(KB)+18)  \
  VMW(12,3)  CON(3,(KB)+19)  \
  VMW(11,4)  CON(4,(KB)+20)  \
  VMW(10,5)  CON(5,(KB)+21)  \
  VMW(9,6)   CON(6,(KB)+22)  \
  VMW(8,7)   CON(7,(KB)+23)  \
  VMW(7,8)   CON(8,(KB)+24)  \
  VMW(6,9)   CON(9,(KB)+25)  \
  VMW(5,10)  CON(10,(KB)+26) \
  VMW(4,11)  CON(11,(KB)+27) \
  VMW(3,12)  CON(12,(KB)+28) \
  VMW(2,13)  CON(13,(KB)+29) \
  VMW(1,14)  CON(14,(KB)+30) \
  VMW(0,15)  CON(15,(KB)+31)

// ---------------- elementwise helpers ----------------
__global__ void k_f32_to_bf16(const float* __restrict__ in, ushort* __restrict__ out, int n) {
  int i = (blockIdx.x * blockDim.x + threadIdx.x) * 4;
  if (i >= n) return;
  const float4 v = *reinterpret_cast<const float4*>(in + i);
  ushort4 o; o.x = f2bf(v.x); o.y = f2bf(v.y); o.z = f2bf(v.z); o.w = f2bf(v.w);
  *reinterpret_cast<ushort4*>(out + i) = o;
}
__global__ void k_zero(int* p, int n) {
  int i = blockIdx.x * blockDim.x + threadIdx.x;
  if (i < n) p[i] = 0;
}

// ---------------- persistent fused scan, split-half pipelined ----------------
struct ScanP {
  const ushort* wih; const ushort* whh;
  const ushort* xb;  const ushort* hinit;
  ushort* h0r;                            // layer-0 h ring (T_STEPS slots)
  ushort* h1r;                            // layer-1 h ring (T_STEPS slots)
  const float* c0; const float* bi; const float* bh;
  float* out; int* bar;
};

// Split barrier primitives (monotonic, relaxed-only, no resets).
__device__ __forceinline__ void garrive(int* gb, int stripe) {
  __syncthreads();  // compiler drains vmcnt: h-store + load-back committed
  if (threadIdx.x == 0)
    __hip_atomic_fetch_add(gb + stripe * 16, 1, __ATOMIC_RELAXED, __HIP_MEMORY_SCOPE_AGENT);
}
__device__ __forceinline__ void gwait(int* gb, int target, bool isRoot) {
  if (threadIdx.x == 0) {
    if (isRoot) {
      const int need = target * GBLK;
      for (;;) {
        int sum = 0;
#pragma unroll
        for (int i = 0; i < 16; ++i)
          sum += __hip_atomic_load(gb + i * 16, __ATOMIC_RELAXED, __HIP_MEMORY_SCOPE_AGENT);
        if (sum >= need) break;
        __builtin_amdgcn_s_sleep(1);
      }
      __hip_atomic_store(gb + 256, target, __ATOMIC_RELAXED, __HIP_MEMORY_SCOPE_AGENT);
    } else {
      while (__hip_atomic_load(gb + 256, __ATOMIC_RELAXED, __HIP_MEMORY_SCOPE_AGENT) < target)
        __builtin_amdgcn_s_sleep(2);
    }
  }
  __syncthreads();
  __builtin_amdgcn_sched_barrier(0);
}

// 256 blocks x 256 threads. Group 0 (blocks 0..127) = layer 0; group 1 = layer 1.
// Per step: EARLY half (dependency-free) overlaps the group barrier's
// publish/detect latency; own-group wait; LATE half (h-dependent); epilogue.
// L1's cross-layer gate uses a cached monotonic watermark (seen0) -> ~free.
__global__ __launch_bounds__(256, 1) void k_scan(ScanP p) {
  __shared__ __align__(16) ushort Wl[32 * 2048];  // 128 KB
  __shared__ float glds[64 * 33];
  const int tid = threadIdx.x, wave = tid >> 6, lane = tid & 63;
  const bool isL1 = blockIdx.x >= 128;
  const int cb = isL1 ? (int)blockIdx.x - 128 : (int)blockIdx.x;
  const int j0 = cb * 8;
  const int stripe = cb & 15;
  const bool isRoot = (cb == 0);
  int* gb = p.bar + (isL1 ? 512 : 0);
  int* rel0 = p.bar + 256;

  const ushort* wihL = p.wih + (isL1 ? (size_t)NGATE * HID : 0);
  const ushort* whhL = p.whh + (isL1 ? (size_t)NGATE * HID : 0);
  for (int q = wave; q < 128; q += 4) {
    const int i = q >> 2, ch = q & 3;
    const ushort* base = (ch < 2) ? wihL : whhL;
    const int g = (i >> 3) * 1024 + j0 + (i & 7);
    gll16(base + (size_t)g * 1024 + (ch & 1) * 512 + (((lane * 16) ^ ((i & 7) << 4)) >> 1),
          (char*)Wl + i * 4096 + ch * 1024);
  }

  // epilogue geometry: thread owns (b = tid>>2, j = j0 + (tid&3)*2 + {0,1})
  const int eb  = tid >> 2;
  const int jl0 = (tid & 3) * 2;
  const int jj  = j0 + jl0;
  const int lofs = isL1 ? NGATE : 0;
  float creg[2], bias[4][2];
#pragma unroll
  for (int i = 0; i < 2; ++i) creg[i] = p.c0[(isL1 ? BH : 0) + eb * 1024 + jj + i];
#pragma unroll
  for (int g = 0; g < 4; ++g)
#pragma unroll
    for (int i = 0; i < 2; ++i)
      bias[g][i] = p.bi[lofs + g * 1024 + jj + i] + p.bh[lofs + g * 1024 + jj + i];

  const size_t aoff = (size_t)(wave * 16 + (lane & 15)) * 1024 + (size_t)((lane >> 4) * 8);
  const int r0 = lane & 15;
  const char* bb0 = (const char*)Wl + r0 * 4096;
  const char* bb1 = (const char*)Wl + (r0 + 16) * 4096;
  const int bsw = (r0 & 7) << 4;
  const int kb = (lane >> 4) * 16;

  int seen0 = 0;  // cached rel0 watermark (thread 0 only)

  __syncthreads();  // W staged

  for (int t = 0; t < T_STEPS; ++t) {
    f32x4 accA = {0.f, 0.f, 0.f, 0.f}, accB = {0.f, 0.f, 0.f, 0.f};
    short8 fr[16];

    if (!isL1) {
      { const ushort* Pp = p.xb + (size_t)t * BH + aoff;          // EARLY: x_t
        PIPE32(Pp, 0) }
      if (t > 0) gwait(gb, t, isRoot);                            // own group t-1 done
      { const ushort* Qp = ((t == 0) ? p.hinit
                                     : p.h0r + (size_t)(t - 1) * BH) + aoff;
        PIPE32(Qp, 32) }                                          // LATE: h0[t-1]
    } else {
      if (threadIdx.x == 0 && seen0 < t + 1) {                    // cross gate: h0[t]
        int v = __hip_atomic_load(rel0, __ATOMIC_RELAXED, __HIP_MEMORY_SCOPE_AGENT);
        while (v < t + 1) {
          __builtin_amdgcn_s_sleep(2);
          v = __hip_atomic_load(rel0, __ATOMIC_RELAXED, __HIP_MEMORY_SCOPE_AGENT);
        }
        seen0 = v;
      }
      __syncthreads();
      __builtin_amdgcn_sched_barrier(0);
      { const ushort* Pp = p.h0r + (size_t)t * BH + aoff;         // EARLY: h0[t]
        PIPE32(Pp, 0) }
      if (t > 0) gwait(gb, t, isRoot);                            // own group t-1 done
      { const ushort* Qp = ((t == 0) ? p.hinit + BH
                                     : p.h1r + (size_t)(t - 1) * BH) + aoff;
        PIPE32(Qp, 32) }                                          // LATE: h1[t-1]
    }

#pragma unroll
    for (int r = 0; r < 4; ++r) {
      const int row = wave * 16 + (lane >> 4) * 4 + r;
      glds[row * 33 + r0]      = accA[r];
      glds[row * 33 + 16 + r0] = accB[r];
    }
    __syncthreads();

    float hres[2];
#pragma unroll
    for (int i = 0; i < 2; ++i) {
      const int jl = jl0 + i;
      const float gi = glds[eb * 33 + jl]      + bias[0][i];
      const float gf = glds[eb * 33 + 8 + jl]  + bias[1][i];
      const float gg = glds[eb * 33 + 16 + jl] + bias[2][i];
      const float go = glds[eb * 33 + 24 + jl] + bias[3][i];
      float c = creg[i];
      const float si = 1.f / (1.f + __expf(-gi));
      const float sf = 1.f / (1.f + __expf(-gf));
      const float so = 1.f / (1.f + __expf(-go));
      const float tg = tanhf(gg);
      c = sf * c + si * tg;
      hres[i] = so * tanhf(c);
      creg[i] = c;
    }

    const uint32_t packed = (uint32_t)f2bf(hres[0]) | ((uint32_t)f2bf(hres[1]) << 16);
    ushort* hdst = (!isL1) ? (p.h0r + (size_t)t * BH) : (p.h1r + (size_t)t * BH);
    uint32_t* hw = (uint32_t*)(hdst + eb * 1024 + jj);
    __hip_atomic_store(hw, packed, __ATOMIC_RELAXED, __HIP_MEMORY_SCOPE_AGENT);
    // same-address load-back: store committed at coherence point before arrive
    uint32_t chk = __hip_atomic_load(hw, __ATOMIC_RELAXED, __HIP_MEMORY_SCOPE_AGENT);
    asm volatile("" :: "v"(chk));

    if (isL1) {
#pragma unroll
      for (int i = 0; i < 2; ++i)
        p.out[(size_t)t * BH + eb * 1024 + jj + i] = hres[i];
      if (t == T_STEPS - 1) {
#pragma unroll
        for (int i = 0; i < 2; ++i) {
          p.out[(size_t)TBH + BH + eb * 1024 + jj + i] = hres[i];
          p.out[(size_t)TBH + 3 * BH + eb * 1024 + jj + i] = creg[i];
        }
      }
    } else if (t == T_STEPS - 1) {
#pragma unroll
      for (int i = 0; i < 2; ++i) {
        p.out[(size_t)TBH + eb * 1024 + jj + i] = hres[i];
        p.out[(size_t)TBH + 2 * BH + eb * 1024 + jj + i] = creg[i];
      }
    }

    garrive(gb, stripe);
  }

  // tail publisher: L1 steps 510/511 need rel0 >= 511/512, beyond the loop's max
  // in-loop publish (511). Root0 confirms all L0 arrivals then publishes 513.
  if (!isL1 && isRoot && threadIdx.x == 0) {
    const int need = T_STEPS * GBLK;
    for (;;) {
      int sum = 0;
#pragma unroll
      for (int i = 0; i < 16; ++i)
        sum += __hip_atomic_load(gb + i * 16, __ATOMIC_RELAXED, __HIP_MEMORY_SCOPE_AGENT);
      if (sum >= need) break;
      __builtin_amdgcn_s_sleep(1);
    }
    __hip_atomic_store(gb + 256, T_STEPS + 1, __ATOMIC_RELAXED, __HIP_MEMORY_SCOPE_AGENT);
  }
}

// ---------------- host ----------------
extern "C" void kernel_launch(void* const* d_in, const int* in_sizes, int n_in,
                              void* d_out, int out_size, void* d_ws, size_t ws_size,
                              hipStream_t stream) {
  const float* x    = (const float*)d_in[0];
  const float* h0   = (const float*)d_in[1];
  const float* c0   = (const float*)d_in[2];
  const float* w_ih = (const float*)d_in[3];
  const float* w_hh = (const float*)d_in[4];
  const float* b_ih = (const float*)d_in[5];
  const float* b_hh = (const float*)d_in[6];
  float* out = (float*)d_out;

  ushort* xb    = (ushort*)d_ws;
  ushort* wihb  = xb + (size_t)TBH;
  ushort* whhb  = wihb + WEL;
  ushort* hinit = whhb + WEL;
  ushort* h0r   = hinit + 2 * (size_t)BH;            // ring: T_STEPS slots
  ushort* h1r   = h0r + (size_t)TBH;                 // ring: T_STEPS slots
  int*    bar   = (int*)(h1r + (size_t)TBH);

  const size_t need = ((size_t)3 * TBH + 2 * WEL + 2 * (size_t)BH) * 2 + 4096;
  if (ws_size < need) return;  // loud failure: d_out stays poisoned

  { int n = TBH;        k_f32_to_bf16<<<(n / 4 + 255) / 256, 256, 0, stream>>>(x, xb, n); }
  { int n = (int)WEL;   k_f32_to_bf16<<<(n / 4 + 255) / 256, 256, 0, stream>>>(w_ih, wihb, n); }
  { int n = (int)WEL;   k_f32_to_bf16<<<(n / 4 + 255) / 256, 256, 0, stream>>>(w_hh, whhb, n); }
  { int n = 2 * BH;     k_f32_to_bf16<<<(n / 4 + 255) / 256, 256, 0, stream>>>(h0, hinit, n); }
  k_zero<<<4, 256, 0, stream>>>(bar, 1024);

  ScanP sp;
  sp.wih = wihb; sp.whh = whhb;
  sp.xb = xb; sp.hinit = hinit;
  sp.h0r = h0r; sp.h1r = h1r;
  sp.c0 = c0; sp.bi = b_ih; sp.bh = b_hh;
  sp.out = out; sp.bar = bar;

  void* kp[1] = {&sp};
  hipLaunchCooperativeKernel(reinterpret_cast<void*>(&k_scan),
                             dim3(256), dim3(256), kp, 0, stream);
}